// Round 9
// baseline (79.929 us; speedup 1.0000x reference)
//
#include <hip/hip_runtime.h>

#define B_ 64
#define H_ 384
#define W_ 384
#define C_ 3
#define TILE 16
#define TILES_X 24            // 384/16
#define TILES_PER_IMG 576     // 24*24
#define GRID (B_ * TILES_PER_IMG)   // 36864, %8==0
#define IMG_PX (H_ * W_)
#define LDS_PX 2730           // 2730*12B = 32760B -> 5 blocks/CU

struct Tap { float v0, v1, v2; };   // 12B -> global_load/store_dwordx3

// The exact per-op-rounded f32 pipeline (numpy-replicating). Shared by the
// per-pixel path AND the corner bbox eval => bounds are exact by monotonicity.
__device__ __forceinline__ void map_xy(
    int i, int j,
    float th0, float th1, float th2, float th3, float th4, float th5,
    float& x, float& y)
{
    const double STEP = 2.0 / 383.0;
    float xs = (j == W_ - 1) ? 1.0f : (float)((double)j * STEP - 1.0);
    float ys = (i == H_ - 1) ? 1.0f : (float)((double)i * STEP - 1.0);
    float t0 = __fadd_rn(__fadd_rn(__fmul_rn(th0, xs), __fmul_rn(th1, ys)), th2);
    float t1 = __fadd_rn(__fadd_rn(__fmul_rn(th3, xs), __fmul_rn(th4, ys)), th5);
    x = __fmul_rn(__fadd_rn(t0, 1.0f), (float)(W_ * 0.5));
    y = __fmul_rn(__fadd_rn(t1, 1.0f), (float)(H_ * 0.5));
}

__global__ __launch_bounds__(256, 5) void bilerp_kernel(
    const float* __restrict__ images,
    const float* __restrict__ theta,
    float* __restrict__ out)
{
    __shared__ float lds[LDS_PX * 3];

    // bijective chunked XCD swizzle (GRID % 8 == 0)
    int bid = blockIdx.x;
    int lbid = (bid & 7) * (GRID / 8) + (bid >> 3);

    int b  = lbid / TILES_PER_IMG;
    int t  = lbid - b * TILES_PER_IMG;
    int ti = t / TILES_X;
    int tj = t - ti * TILES_X;
    int i0 = ti * TILE, j0 = tj * TILE;

    int tid = threadIdx.x;
    int ty = tid >> 4, tx = tid & 15;
    int i = i0 + ty, j = j0 + tx;

    const float* th = theta + b * 6;
    float th0 = th[0], th1 = th[1], th2 = th[2];
    float th3 = th[3], th4 = th[4], th5 = th[5];
    const float* img = images + (size_t)b * (IMG_PX * C_);
    float* outb = out + (size_t)b * (IMG_PX * C_);

    // ---- exact input bbox from the 4 tile corners ----
    float xA, yA, xB, yB, xC, yC, xD, yD;
    map_xy(i0,          j0,          th0, th1, th2, th3, th4, th5, xA, yA);
    map_xy(i0,          j0 + TILE-1, th0, th1, th2, th3, th4, th5, xB, yB);
    map_xy(i0 + TILE-1, j0,          th0, th1, th2, th3, th4, th5, xC, yC);
    map_xy(i0 + TILE-1, j0 + TILE-1, th0, th1, th2, th3, th4, th5, xD, yD);
    float xmin = fminf(fminf(xA, xB), fminf(xC, xD));
    float xmax = fmaxf(fmaxf(xA, xB), fmaxf(xC, xD));
    float ymin = fminf(fminf(yA, yB), fminf(yC, yD));
    float ymax = fmaxf(fmaxf(yA, yB), fmaxf(yC, yD));

    int XL = min(max((int)floorf(xmin), 0), W_ - 1);
    int XH = min(max((int)floorf(xmax) + 1, 0), W_ - 1);
    int YL = min(max((int)floorf(ymin), 0), H_ - 1);
    int YH = min(max((int)floorf(ymax) + 1, 0), H_ - 1);
    int ncols = XH - XL + 1;
    int nrows = YH - YL + 1;
    int npx = ncols * nrows;

    // ---- per-pixel coords/weights (bit-identical to the passing kernel) ----
    float x, y;
    map_xy(i, j, th0, th1, th2, th3, th4, th5, x, y);

    float fx = floorf(x);
    float fy = floorf(y);
    int x0 = min(max((int)fx, 0), W_ - 1);
    int x1 = min(max((int)fx + 1, 0), W_ - 1);
    int y0 = min(max((int)fy, 0), H_ - 1);
    int y1 = min(max((int)fy + 1, 0), H_ - 1);

    float xc = fminf(fmaxf(x, 0.0f), (float)(W_ - 1));
    float yc = fminf(fmaxf(y, 0.0f), (float)(H_ - 1));

    float x0f = (float)x0, x1f = (float)x1;
    float y0f = (float)y0, y1f = (float)y1;

    float wx0 = __fsub_rn(x1f, xc);
    float wx1 = __fsub_rn(xc, x0f);
    float wy0 = __fsub_rn(y1f, yc);
    float wy1 = __fsub_rn(yc, y0f);

    float wa = __fmul_rn(wx0, wy0);
    float wb = __fmul_rn(wx0, wy1);
    float wc = __fmul_rn(wx1, wy0);
    float wd = __fmul_rn(wx1, wy1);

    Tap A, Bv, Cv, D;

    if (npx <= LDS_PX) {
        // ---- staged path: coalesced bbox load -> LDS, gather from LDS ----
        for (int p = tid; p < npx; p += 256) {
            int r = (int)((unsigned)p / (unsigned)ncols);
            int c = p - r * ncols;
            const float* s = img + ((size_t)(YL + r) * W_ + (XL + c)) * C_;
            int d = p * 3;
            float v0 = s[0], v1 = s[1], v2 = s[2];
            lds[d + 0] = v0;
            lds[d + 1] = v1;
            lds[d + 2] = v2;
        }
        __syncthreads();

        int la = ((y0 - YL) * ncols + (x0 - XL)) * 3;
        int lb = ((y1 - YL) * ncols + (x0 - XL)) * 3;
        int lc = ((y0 - YL) * ncols + (x1 - XL)) * 3;
        int ld = ((y1 - YL) * ncols + (x1 - XL)) * 3;
        A.v0  = lds[la + 0]; A.v1  = lds[la + 1]; A.v2  = lds[la + 2];
        Bv.v0 = lds[lb + 0]; Bv.v1 = lds[lb + 1]; Bv.v2 = lds[lb + 2];
        Cv.v0 = lds[lc + 0]; Cv.v1 = lds[lc + 1]; Cv.v2 = lds[lc + 2];
        D.v0  = lds[ld + 0]; D.v1  = lds[ld + 1]; D.v2  = lds[ld + 2];
    } else {
        // ---- fallback: direct global gathers (block-uniform branch) ----
        A  = *(const Tap*)(img + (y0 * W_ + x0) * C_);
        Bv = *(const Tap*)(img + (y1 * W_ + x0) * C_);
        Cv = *(const Tap*)(img + (y0 * W_ + x1) * C_);
        D  = *(const Tap*)(img + (y1 * W_ + x1) * C_);
    }

    // ---- weighted sum, per-op rounded f32 (identical association) ----
    float r0 = __fadd_rn(
        __fadd_rn(
            __fadd_rn(__fmul_rn(wa, A.v0), __fmul_rn(wb, Bv.v0)),
            __fmul_rn(wc, Cv.v0)),
        __fmul_rn(wd, D.v0));
    float r1 = __fadd_rn(
        __fadd_rn(
            __fadd_rn(__fmul_rn(wa, A.v1), __fmul_rn(wb, Bv.v1)),
            __fmul_rn(wc, Cv.v1)),
        __fmul_rn(wd, D.v1));
    float r2 = __fadd_rn(
        __fadd_rn(
            __fadd_rn(__fmul_rn(wa, A.v2), __fmul_rn(wb, Bv.v2)),
            __fmul_rn(wc, Cv.v2)),
        __fmul_rn(wd, D.v2));

    Tap* o = (Tap*)(outb + ((size_t)i * W_ + j) * C_);
    Tap v = { r0, r1, r2 };
    *o = v;
}

extern "C" void kernel_launch(void* const* d_in, const int* in_sizes, int n_in,
                              void* d_out, int out_size, void* d_ws, size_t ws_size,
                              hipStream_t stream) {
    const float* images = (const float*)d_in[0];
    const float* theta  = (const float*)d_in[1];
    float* out = (float*)d_out;

    bilerp_kernel<<<GRID, 256, 0, stream>>>(images, theta, out);
}